// Round 8
// baseline (804.716 us; speedup 1.0000x reference)
//
#include <hip/hip_runtime.h>
#include <hip/hip_bf16.h>

#define N_NODES 100000
#define N_EDGES 1200000

typedef __attribute__((ext_vector_type(8))) short bfrag;
typedef __attribute__((ext_vector_type(4))) float ffrag;
typedef __attribute__((ext_vector_type(4))) float nf4;   // native vec for nontemporal
typedef __attribute__((ext_vector_type(2))) float nf2;

union FragU { uint4 v; uint32_t u[4]; bfrag f; };

__device__ __forceinline__ ushort bfbits(float a) {
  union { __hip_bfloat16 h; ushort u; } c; c.h = __float2bfloat16(a); return c.u;
}
__device__ __forceinline__ uint32_t pkbf(float a, float b) {
  union { __hip_bfloat162 h; uint32_t u; } c;
  c.h = __float22bfloat162_rn(float2{a, b}); return c.u;
}
__device__ __forceinline__ uint32_t mul2bf(uint32_t a, uint32_t b) {
  union { uint32_t u; __hip_bfloat162 h; } x, y, r;
  x.u = a; y.u = b; r.h = __hmul2(x.h, y.h); return r.u;
}
__device__ __forceinline__ float bflo(uint32_t u) { return __int_as_float(u << 16); }
__device__ __forceinline__ float bfhi(uint32_t u) { return __int_as_float(u & 0xffff0000u); }

// 16-lane butterfly add via DPP (VALU pipe, not LDS).
template <int CTRL>
__device__ __forceinline__ float dpp_add16(float v) {
  int x = __builtin_amdgcn_update_dpp(0, __float_as_int(v), CTRL, 0xF, 0xF, true);
  return v + __int_as_float(x);
}
__device__ __forceinline__ float reduce16(float v) {
  v = dpp_add16<0xB1>(v);   // quad_perm [1,0,3,2]  : xor 1
  v = dpp_add16<0x4E>(v);   // quad_perm [2,3,0,1]  : xor 2
  v = dpp_add16<0x141>(v);  // row_half_mirror      : xor 7
  v = dpp_add16<0x140>(v);  // row_mirror           : xor 15
  return v;
}

// ---------------- x -> bf16 ----------------

__global__ void cvt_k(const float* __restrict__ x, ushort* __restrict__ xb, int n2) {
  int i = blockIdx.x * blockDim.x + threadIdx.x;   // n2 = N*32 (pairs)
  if (i < n2) {
    nf2 v = __builtin_nontemporal_load(((const nf2*)x) + i);
    ((uint32_t*)xb)[i] = pkbf(v.x, v.y);
  }
}

// ---------------- CSR build ----------------

__global__ void hist_k(const int* __restrict__ ei, int* __restrict__ deg,
                       int* __restrict__ rank, int E) {
  int e = blockIdx.x * blockDim.x + threadIdx.x;
  if (e < E) rank[e] = atomicAdd(&deg[ei[E + e]], 1);
}

__global__ __launch_bounds__(1024) void scan1_k(const int* __restrict__ deg,
                                                int* __restrict__ off,
                                                int* __restrict__ bsum, int n) {
  __shared__ int wpart[16];
  __shared__ int wpre[16];
  int tid = threadIdx.x, lane = tid & 63, wid = tid >> 6;
  int i = blockIdx.x * 1024 + tid;
  int v = (i < n) ? deg[i] : 0;
  int x = v;
  #pragma unroll
  for (int o = 1; o < 64; o <<= 1) {
    int y = __shfl_up(x, o);
    if (lane >= o) x += y;
  }
  if (lane == 63) wpart[wid] = x;
  __syncthreads();
  if (tid == 0) {
    int run = 0;
    #pragma unroll
    for (int w = 0; w < 16; w++) { int t = wpart[w]; wpre[w] = run; run += t; }
    bsum[blockIdx.x] = run;
  }
  __syncthreads();
  if (i < n) off[i] = x - v + wpre[wid];
}

__global__ void scan2_k(const int* __restrict__ bsum, int* __restrict__ bpre,
                        int* __restrict__ off, int nb, int n) {
  if (threadIdx.x == 0) {
    int run = 0;
    for (int b = 0; b < nb; b++) { int t = bsum[b]; bpre[b] = run; run += t; }
    off[n] = run;
  }
}

__global__ __launch_bounds__(1024) void scan3_k(int* __restrict__ off,
                                                const int* __restrict__ bpre, int n) {
  int i = blockIdx.x * 1024 + threadIdx.x;
  if (i < n) off[i] += bpre[blockIdx.x];
}

__global__ void fill_k(const int* __restrict__ ei, const int* __restrict__ off,
                       const int* __restrict__ rank, int* __restrict__ csr, int E) {
  int e = blockIdx.x * blockDim.x + threadIdx.x;
  if (e < E) {
    int d = ei[E + e];
    int p = off[d] + rank[e];
    __builtin_nontemporal_store(ei[e], &csr[p]);
  }
}

// ---------------- mean aggregation: 4 nodes/wave, batch-16 gathers ----------

__global__ __launch_bounds__(256) void agg_k(
    const ushort* __restrict__ Xb, const int* __restrict__ off, const int* __restrict__ csr,
    ushort* __restrict__ aggout, int n) {
  int lane = threadIdx.x & 63;
  int quad = lane >> 4, f8 = lane & 15;
  int wave = blockIdx.x * 4 + (threadIdx.x >> 6);
  int nw = gridDim.x * 4;
  int nquads = (n + 3) >> 2;
  const uint2* X2 = (const uint2*)Xb;
  for (int p = wave; p < nquads; p += nw) {
    int i = p * 4 + quad;
    int ic = i < n ? i : n - 1;
    int s0 = off[ic], s1 = off[ic + 1];
    float a0 = 0.f, a1 = 0.f, a2 = 0.f, a3 = 0.f;
    for (int j = s0; j < s1; j += 16) {
      int id[16]; uint2 us[16];
      #pragma unroll
      for (int u = 0; u < 16; u++) {
        int jj = j + u;
        id[u] = csr[jj < s1 ? jj : s1 - 1];
      }
      #pragma unroll
      for (int u = 0; u < 16; u++) us[u] = X2[(size_t)id[u] * 16 + f8];
      #pragma unroll
      for (int u = 0; u < 16; u++) {
        if (j + u < s1) {
          a0 += bflo(us[u].x); a1 += bfhi(us[u].x);
          a2 += bflo(us[u].y); a3 += bfhi(us[u].y);
        }
      }
    }
    if (i < n) {
      float rdeg = 1.f / fmaxf((float)(s1 - s0), 1.f);
      uint2 w;
      w.x = pkbf(a0 * rdeg, a1 * rdeg);
      w.y = pkbf(a2 * rdeg, a3 * rdeg);
      ((uint2*)aggout)[(size_t)i * 16 + f8] = w;
    }
  }
}

// ---------------- node linear + LN + relu via MFMA, 2-set pipeline ----------

__global__ __launch_bounds__(256) void node_k(
    const ushort* __restrict__ agg, const ushort* __restrict__ selfb,
    const float* __restrict__ wl, const float* __restrict__ wr,
    const float* __restrict__ bias, const float* __restrict__ g, const float* __restrict__ lb,
    ushort* __restrict__ outb, int n) {
  __shared__ ushort wt[64 * 128];   // [n][k] swizzled, 16KB
  const int tid = threadIdx.x;
  for (int i = tid; i < 8192; i += 256) {
    int k = i >> 6, nn = i & 63;
    float v = (k < 64) ? wl[k * 64 + nn] : wr[(k - 64) * 64 + nn];
    wt[nn * 128 + (((k >> 3) ^ (nn & 7)) * 8) + (k & 7)] = bfbits(v);
  }
  __syncthreads();
  const int lane = tid & 63, wid = tid >> 6;
  const int ln = lane & 15, q = lane >> 4;
  float bias_n[4], g_n[4], lb_n[4];
  #pragma unroll
  for (int nt = 0; nt < 4; nt++) {
    bias_n[nt] = bias[nt * 16 + ln];
    g_n[nt] = g[nt * 16 + ln];
    lb_n[nt] = lb[nt * 16 + ln];
  }
  const int ntiles = (n + 15) >> 4;
  const int S = gridDim.x * 4;
  int t0 = blockIdx.x * 4 + wid;

  auto loadfrag = [&](FragU (&afr)[4], int t) {
    int tc = t < ntiles ? t : ntiles - 1;
    int node = tc * 16 + ln;
    int nc = node < n ? node : n - 1;
    #pragma unroll
    for (int kk = 0; kk < 2; kk++) {
      afr[kk].v     = ((const uint4*)agg)[(size_t)nc * 8 + kk * 4 + q];
      afr[2 + kk].v = ((const uint4*)selfb)[(size_t)nc * 8 + kk * 4 + q];
    }
  };

  auto compute = [&](FragU (&afr)[4], int t) {
    ffrag acc[4];
    #pragma unroll
    for (int nt = 0; nt < 4; nt++) acc[nt] = ffrag{0.f, 0.f, 0.f, 0.f};
    #pragma unroll
    for (int kk = 0; kk < 4; kk++) {
      bfrag a = afr[kk].f;
      #pragma unroll
      for (int nt = 0; nt < 4; nt++) {
        int nn = nt * 16 + ln;
        int b = kk * 4 + q;
        const bfrag* bp = (const bfrag*)&wt[nn * 128 + ((b ^ (nn & 7)) * 8)];
        acc[nt] = __builtin_amdgcn_mfma_f32_16x16x32_bf16(a, *bp, acc[nt], 0, 0, 0);
      }
    }
    #pragma unroll
    for (int r = 0; r < 4; r++) {
      int m = t * 16 + q * 4 + r;
      float o[4];
      #pragma unroll
      for (int nt = 0; nt < 4; nt++) o[nt] = acc[nt][r] + bias_n[nt];
      float s = (o[0] + o[1]) + (o[2] + o[3]);
      s = reduce16(s);
      float mu = s * (1.f / 64.f);
      float v2 = 0.f;
      #pragma unroll
      for (int nt = 0; nt < 4; nt++) { float d2 = o[nt] - mu; v2 += d2 * d2; }
      v2 = reduce16(v2);
      float rs = rsqrtf(v2 * (1.f / 64.f) + 1e-5f);
      if (m < n) {
        #pragma unroll
        for (int nt = 0; nt < 4; nt++) {
          float y = fmaxf((o[nt] - mu) * rs * g_n[nt] + lb_n[nt], 0.f);
          outb[(size_t)m * 64 + nt * 16 + ln] = bfbits(y);
        }
      }
    }
  };

  if (t0 >= ntiles) return;
  FragU fA[4], fB[4];
  loadfrag(fA, t0);
  loadfrag(fB, t0 + S);
  for (int t = t0; t < ntiles; t += 2 * S) {
    compute(fA, t);
    loadfrag(fA, t + 2 * S);        // issued 1 compute ahead of its wait
    if (t + S < ntiles) compute(fB, t + S);
    loadfrag(fB, t + 3 * S);
  }
}

// ---------------- edge classifier: 3-set pipeline + 4 blocks/CU ---------------
// Round 7 counters: MfmaUtil 17, VALU 32, HBM 26%, occupancy 21% (= the
// launch_bounds(256,2) x grid-512 cap of 8 waves/CU). Latency-bound with
// nothing saturated -> double TLP: VGPR 120 <= 128 and LDS 36KB <= 40KB both
// permit 4 blocks/CU. launch_bounds(256,4) + grid 1024.

__global__ __launch_bounds__(256, 4) void edge_mfma_k(
    const int* __restrict__ ei, const float* __restrict__ ea,
    const ushort* __restrict__ zb,
    const float* __restrict__ cw1, const float* __restrict__ cb1,
    const float* __restrict__ cw2, const float* __restrict__ cb2,
    const float* __restrict__ cw3, const float* __restrict__ cb3,
    float* __restrict__ out, int E) {
  __shared__ ushort smem[64 * 256];   // 32KB: W1^T swizzled staging, then h1 tiles
  __shared__ ushort ws2[2048];        // 4KB: W2^T B-fragments [t2*2+kk][lane]*8
  const int tid = threadIdx.x;

  for (int i = tid; i < 224 * 64; i += 256) {
    int k = i >> 6, n = i & 63;
    int blk = k >> 3;
    smem[n * 256 + ((blk ^ (n & 7)) * 8) + (k & 7)] = bfbits(cw1[i]);
  }
  __syncthreads();

  const int lane = tid & 63, wid = tid >> 6;
  const int ln = lane & 15, q = lane >> 4;

  // W1 B-fragments -> 112 persistent AGPR/VGPRs (read LDS exactly once)
  FragU w1f[7][4];
  #pragma unroll
  for (int kk = 0; kk < 7; kk++) {
    #pragma unroll
    for (int tt = 0; tt < 4; tt++) {
      int n = tt * 16 + ln;
      int b = kk * 4 + q;
      w1f[kk][tt].v = *(const uint4*)&smem[n * 256 + ((b ^ (n & 7)) * 8)];
    }
  }
  // W2^T B-fragments -> LDS table
  if (wid == 0) {
    #pragma unroll
    for (int t2 = 0; t2 < 2; t2++) {
      #pragma unroll
      for (int kk = 0; kk < 2; kk++) {
        uint32_t w[4];
        #pragma unroll
        for (int p = 0; p < 4; p++) {
          int k = kk * 32 + q * 8 + p * 2;
          int n = t2 * 16 + ln;
          w[p] = pkbf(cw2[k * 32 + n], cw2[(k + 1) * 32 + n]);
        }
        *(uint4*)&ws2[((t2 * 2 + kk) * 64 + lane) * 8] = make_uint4(w[0], w[1], w[2], w[3]);
      }
    }
  }
  __syncthreads();                    // W1 staging dead; reuse as h1 tiles
  ushort* hb = &smem[wid * 1024];     // 16x64 bf16 per wave (2KB)

  float cb1v[4];
  #pragma unroll
  for (int t = 0; t < 4; t++) cb1v[t] = cb1[t * 16 + ln];
  float cb2a = cb2[ln], cb2b = cb2[16 + ln];
  float w3a = cw3[ln], w3b = cw3[16 + ln];
  float cb3v = cb3[0];

  const int nt = E >> 4;
  const int S = gridDim.x * 4;
  const int S3 = 3 * S;
  const int w0 = blockIdx.x * 4 + wid;
  const uint4* Z4 = (const uint4*)zb;
  const nf4* EA4 = (const nf4*)ea;

  FragU zA[4], zB[4], zC[4];
  int svA, dvA, svB, dvB, svC, dvC;

  // prologue: issue z for u, load ei values for u+S3 (in flight)
  auto prol = [&](FragU (&z)[4], int &sv, int &dv, int u) {
    int uc = u < nt ? u : nt - 1;
    int e = uc * 16 + ln;
    int s = __builtin_nontemporal_load(ei + e);
    int d = __builtin_nontemporal_load(ei + E + e);
    z[0].v = Z4[(size_t)s * 8 + q];
    z[1].v = Z4[(size_t)s * 8 + 4 + q];
    z[2].v = Z4[(size_t)d * 8 + q];
    z[3].v = Z4[(size_t)d * 8 + 4 + q];
    int un = u + S3 < nt ? u + S3 : nt - 1;
    sv = __builtin_nontemporal_load(ei + un * 16 + ln);
    dv = __builtin_nontemporal_load(ei + E + un * 16 + ln);
  };
  prol(zA, svA, dvA, w0);
  prol(zB, svB, dvB, w0 + S);
  prol(zC, svC, dvC, w0 + 2 * S);

  // one pipeline half: compute tile u from z; then refill z for u+S3 (in place)
  // and ei values for u+2*S3 (in place).
  auto half = [&](FragU (&z)[4], int &sv, int &dv, int u) {
    int uc = u < nt ? u : nt - 1;
    int e = uc * 16 + ln;
    // ea issue now; waited at kk=6 (last A-frag) ~400cy later
    nf4 l0 = __builtin_nontemporal_load(EA4 + (size_t)e * 8 + q * 2);
    nf4 l1 = __builtin_nontemporal_load(EA4 + (size_t)e * 8 + q * 2 + 1);

    ffrag acc1[4];
    #pragma unroll
    for (int tt = 0; tt < 4; tt++) acc1[tt] = ffrag{0.f, 0.f, 0.f, 0.f};
    #pragma unroll
    for (int kk = 0; kk < 7; kk++) {
      FragU af;
      if (kk < 4) af = z[kk];
      else if (kk < 6) {
        #pragma unroll
        for (int p = 0; p < 4; p++) af.u[p] = mul2bf(z[kk - 4].u[p], z[kk - 2].u[p]);
      } else {
        af.u[0] = pkbf(l0.x, l0.y); af.u[1] = pkbf(l0.z, l0.w);
        af.u[2] = pkbf(l1.x, l1.y); af.u[3] = pkbf(l1.z, l1.w);
      }
      bfrag a = af.f;
      #pragma unroll
      for (int tt = 0; tt < 4; tt++)
        acc1[tt] = __builtin_amdgcn_mfma_f32_16x16x32_bf16(a, w1f[kk][tt].f, acc1[tt], 0, 0, 0);
    }

    // refill this set: z gathers for u+S3 (addresses ready in sv/dv — no wait)
    {
      z[0].v = Z4[(size_t)sv * 8 + q];
      z[1].v = Z4[(size_t)sv * 8 + 4 + q];
      z[2].v = Z4[(size_t)dv * 8 + q];
      z[3].v = Z4[(size_t)dv * 8 + 4 + q];
      int uf = u + 2 * S3 < nt ? u + 2 * S3 : nt - 1;
      sv = __builtin_nontemporal_load(ei + uf * 16 + ln);
      dv = __builtin_nontemporal_load(ei + E + uf * 16 + ln);
    }

    // h1 = relu(acc1 + cb1) -> swizzled LDS transpose (C-layout -> A-layout)
    #pragma unroll
    for (int tt = 0; tt < 4; tt++) {
      #pragma unroll
      for (int r = 0; r < 4; r++) {
        int m = q * 4 + r;
        int col = tt * 16 + ln;
        float v = fmaxf(acc1[tt][r] + cb1v[tt], 0.f);
        hb[m * 64 + (((col >> 3) ^ (m & 7)) * 8) + (col & 7)] = bfbits(v);
      }
    }

    ffrag acc2[2];
    acc2[0] = ffrag{0.f, 0.f, 0.f, 0.f};
    acc2[1] = ffrag{0.f, 0.f, 0.f, 0.f};
    #pragma unroll
    for (int kk = 0; kk < 2; kk++) {
      int b = kk * 4 + q;
      const bfrag* ap = (const bfrag*)&hb[ln * 64 + ((b ^ (ln & 7)) * 8)];
      bfrag a2 = *ap;
      const bfrag* b0p = (const bfrag*)&ws2[((0 * 2 + kk) * 64 + lane) * 8];
      const bfrag* b1p = (const bfrag*)&ws2[((1 * 2 + kk) * 64 + lane) * 8];
      acc2[0] = __builtin_amdgcn_mfma_f32_16x16x32_bf16(a2, *b0p, acc2[0], 0, 0, 0);
      acc2[1] = __builtin_amdgcn_mfma_f32_16x16x32_bf16(a2, *b1p, acc2[1], 0, 0, 0);
    }

    float p0 = fmaxf(acc2[0][0] + cb2a, 0.f) * w3a + fmaxf(acc2[1][0] + cb2b, 0.f) * w3b;
    float p1 = fmaxf(acc2[0][1] + cb2a, 0.f) * w3a + fmaxf(acc2[1][1] + cb2b, 0.f) * w3b;
    float p2 = fmaxf(acc2[0][2] + cb2a, 0.f) * w3a + fmaxf(acc2[1][2] + cb2b, 0.f) * w3b;
    float p3 = fmaxf(acc2[0][3] + cb2a, 0.f) * w3a + fmaxf(acc2[1][3] + cb2b, 0.f) * w3b;
    p0 = reduce16(p0); p1 = reduce16(p1); p2 = reduce16(p2); p3 = reduce16(p3);
    float keep = (ln == 0) ? p0 : (ln == 1) ? p1 : (ln == 2) ? p2 : p3;
    if (u < nt && ln < 4)
      __builtin_nontemporal_store(keep + cb3v, &out[u * 16 + q * 4 + ln]);
  };

  for (int t = w0; t < nt; t += S3) {
    half(zA, svA, dvA, t);
    half(zB, svB, dvB, t + S);
    half(zC, svC, dvC, t + 2 * S);
  }
}

// ---------------- launch ----------------

extern "C" void kernel_launch(void* const* d_in, const int* in_sizes, int n_in,
                              void* d_out, int out_size, void* d_ws, size_t ws_size,
                              hipStream_t stream) {
  const float* x   = (const float*)d_in[0];
  const int*   ei  = (const int*)d_in[1];
  const float* ea  = (const float*)d_in[2];
  const float* wl0 = (const float*)d_in[3];
  const float* wr0 = (const float*)d_in[4];
  const float* b0  = (const float*)d_in[5];
  const float* g0  = (const float*)d_in[6];
  const float* lb0 = (const float*)d_in[7];
  const float* wl1 = (const float*)d_in[8];
  const float* wr1 = (const float*)d_in[9];
  const float* b1  = (const float*)d_in[10];
  const float* g1  = (const float*)d_in[11];
  const float* lb1 = (const float*)d_in[12];
  const float* cw1 = (const float*)d_in[13];
  const float* cb1 = (const float*)d_in[14];
  const float* cw2 = (const float*)d_in[15];
  const float* cb2 = (const float*)d_in[16];
  const float* cw3 = (const float*)d_in[17];
  const float* cb3 = (const float*)d_in[18];
  float* out = (float*)d_out;
  const int N = N_NODES, E = N_EDGES;
  const int NB = (N + 1023) / 1024;

  uintptr_t pp = (uintptr_t)d_ws;
  auto alloc = [&](size_t bytes) {
    uintptr_t r = (pp + 255) & ~(uintptr_t)255; pp = r + bytes; return (void*)r;
  };
  int* deg  = (int*)alloc((size_t)N * 4);
  int* off  = (int*)alloc((size_t)(N + 1) * 4);
  int* rank = (int*)alloc((size_t)E * 4);
  int* csr  = (int*)alloc((size_t)E * 4);
  int* bsum = (int*)alloc((size_t)NB * 4);
  int* bpre = (int*)alloc((size_t)NB * 4);
  ushort* xb  = (ushort*)alloc((size_t)N * 64 * 2);
  ushort* agg = (ushort*)alloc((size_t)N * 64 * 2);
  ushort* hb  = (ushort*)alloc((size_t)N * 64 * 2);
  ushort* zb  = (ushort*)alloc((size_t)N * 64 * 2);

  hipMemsetAsync(deg, 0, (size_t)N * 4, stream);
  cvt_k<<<(N * 32 + 255) / 256, 256, 0, stream>>>(x, xb, N * 32);
  hist_k<<<(E + 255) / 256, 256, 0, stream>>>(ei, deg, rank, E);
  scan1_k<<<NB, 1024, 0, stream>>>(deg, off, bsum, N);
  scan2_k<<<1, 64, 0, stream>>>(bsum, bpre, off, NB, N);
  scan3_k<<<NB, 1024, 0, stream>>>(off, bpre, N);
  fill_k<<<(E + 255) / 256, 256, 0, stream>>>(ei, off, rank, csr, E);
  // layer 0
  agg_k<<<2048, 256, 0, stream>>>(xb, off, csr, agg, N);
  node_k<<<1024, 256, 0, stream>>>(agg, xb, wl0, wr0, b0, g0, lb0, hb, N);
  // layer 1
  agg_k<<<2048, 256, 0, stream>>>(hb, off, csr, agg, N);
  node_k<<<1024, 256, 0, stream>>>(agg, hb, wl1, wr1, b1, g1, lb1, zb, N);
  // edge classifier
  edge_mfma_k<<<1024, 256, 0, stream>>>(ei, ea, zb, cw1, cb1, cw2, cb2, cw3, cb3, out, E);
}

// Round 9
// 488.562 us; speedup vs baseline: 1.6471x; 1.6471x over previous
//
#include <hip/hip_runtime.h>
#include <hip/hip_bf16.h>

#define N_NODES 100000
#define N_EDGES 1200000

typedef __attribute__((ext_vector_type(8))) short bfrag;
typedef __attribute__((ext_vector_type(4))) float ffrag;
typedef __attribute__((ext_vector_type(4))) float nf4;   // native vec for nontemporal
typedef __attribute__((ext_vector_type(2))) float nf2;

union FragU { uint4 v; uint32_t u[4]; bfrag f; };

__device__ __forceinline__ ushort bfbits(float a) {
  union { __hip_bfloat16 h; ushort u; } c; c.h = __float2bfloat16(a); return c.u;
}
__device__ __forceinline__ uint32_t pkbf(float a, float b) {
  union { __hip_bfloat162 h; uint32_t u; } c;
  c.h = __float22bfloat162_rn(float2{a, b}); return c.u;
}
__device__ __forceinline__ uint32_t mul2bf(uint32_t a, uint32_t b) {
  union { uint32_t u; __hip_bfloat162 h; } x, y, r;
  x.u = a; y.u = b; r.h = __hmul2(x.h, y.h); return r.u;
}
__device__ __forceinline__ float bflo(uint32_t u) { return __int_as_float(u << 16); }
__device__ __forceinline__ float bfhi(uint32_t u) { return __int_as_float(u & 0xffff0000u); }

// DPP helpers (VALU pipe, not LDS).
template <int CTRL>
__device__ __forceinline__ float dpp_addf(float v) {
  int x = __builtin_amdgcn_update_dpp(0, __float_as_int(v), CTRL, 0xF, 0xF, true);
  return v + __int_as_float(x);
}
__device__ __forceinline__ float reduce16(float v) {
  v = dpp_addf<0xB1>(v);   // quad_perm [1,0,3,2]  : xor 1
  v = dpp_addf<0x4E>(v);   // quad_perm [2,3,0,1]  : xor 2
  v = dpp_addf<0x141>(v);  // row_half_mirror      : xor 7
  v = dpp_addf<0x140>(v);  // row_mirror           : xor 15
  return v;
}

// ---------------- x -> bf16 ----------------

__global__ void cvt_k(const float* __restrict__ x, ushort* __restrict__ xb, int n2) {
  int i = blockIdx.x * blockDim.x + threadIdx.x;   // n2 = N*32 (pairs)
  if (i < n2) {
    nf2 v = __builtin_nontemporal_load(((const nf2*)x) + i);
    ((uint32_t*)xb)[i] = pkbf(v.x, v.y);
  }
}

// ---------------- CSR build ----------------

__global__ void hist_k(const int* __restrict__ ei, int* __restrict__ deg,
                       int* __restrict__ rank, int E) {
  int e = blockIdx.x * blockDim.x + threadIdx.x;
  if (e < E) rank[e] = atomicAdd(&deg[ei[E + e]], 1);
}

__global__ __launch_bounds__(1024) void scan1_k(const int* __restrict__ deg,
                                                int* __restrict__ off,
                                                int* __restrict__ bsum, int n) {
  __shared__ int wpart[16];
  __shared__ int wpre[16];
  int tid = threadIdx.x, lane = tid & 63, wid = tid >> 6;
  int i = blockIdx.x * 1024 + tid;
  int v = (i < n) ? deg[i] : 0;
  int x = v;
  #pragma unroll
  for (int o = 1; o < 64; o <<= 1) {
    int y = __shfl_up(x, o);
    if (lane >= o) x += y;
  }
  if (lane == 63) wpart[wid] = x;
  __syncthreads();
  if (tid == 0) {
    int run = 0;
    #pragma unroll
    for (int w = 0; w < 16; w++) { int t = wpart[w]; wpre[w] = run; run += t; }
    bsum[blockIdx.x] = run;
  }
  __syncthreads();
  if (i < n) off[i] = x - v + wpre[wid];
}

__global__ void scan2_k(const int* __restrict__ bsum, int* __restrict__ bpre,
                        int* __restrict__ off, int nb, int n) {
  if (threadIdx.x == 0) {
    int run = 0;
    for (int b = 0; b < nb; b++) { int t = bsum[b]; bpre[b] = run; run += t; }
    off[n] = run;
  }
}

__global__ __launch_bounds__(1024) void scan3_k(int* __restrict__ off,
                                                const int* __restrict__ bpre, int n) {
  int i = blockIdx.x * 1024 + threadIdx.x;
  if (i < n) off[i] += bpre[blockIdx.x];
}

__global__ void fill_k(const int* __restrict__ ei, const int* __restrict__ off,
                       const int* __restrict__ rank, int* __restrict__ csr, int E) {
  int e = blockIdx.x * blockDim.x + threadIdx.x;
  if (e < E) {
    int d = ei[E + e];
    int p = off[d] + rank[e];
    __builtin_nontemporal_store(ei[e], &csr[p]);
  }
}

// ---------------- mean aggregation: uint4 gathers, 2 rows per 16-lane slot ---
// Per node-slot (16 lanes): two 8-lane groups each own one row stream; lane =
// 16B chunk (8 x 16B = 128B row). Batch of 16 rows = 8 csr + 8 uint4 loads per
// lane (was 16+16 with uint2) -> half the VMEM instructions, same bytes.
// Cross-group combine via DPP row_ror:8 (VALU). 8-lane uint4 store (128B).

__global__ __launch_bounds__(256) void agg_k(
    const ushort* __restrict__ Xb, const int* __restrict__ off, const int* __restrict__ csr,
    ushort* __restrict__ aggout, int n) {
  int lane = threadIdx.x & 63;
  int quad = lane >> 4, f8 = lane & 15;
  int g = f8 >> 3, l8 = f8 & 7;       // row-group, 16B-chunk index
  int wave = blockIdx.x * 4 + (threadIdx.x >> 6);
  int nw = gridDim.x * 4;
  int nquads = (n + 3) >> 2;
  const uint4* X4 = (const uint4*)Xb;
  for (int p = wave; p < nquads; p += nw) {
    int i = p * 4 + quad;
    int ic = i < n ? i : n - 1;
    int s0 = off[ic], s1 = off[ic + 1];
    float a0 = 0.f, a1 = 0.f, a2 = 0.f, a3 = 0.f;
    float a4 = 0.f, a5 = 0.f, a6 = 0.f, a7 = 0.f;
    for (int j = s0; j < s1; j += 16) {
      int id[8]; uint4 us[8];
      #pragma unroll
      for (int u = 0; u < 8; u++) {
        int jj = j + u * 2 + g;
        id[u] = csr[jj < s1 ? jj : s1 - 1];
      }
      #pragma unroll
      for (int u = 0; u < 8; u++) us[u] = X4[(size_t)id[u] * 8 + l8];
      #pragma unroll
      for (int u = 0; u < 8; u++) {
        if (j + u * 2 + g < s1) {
          a0 += bflo(us[u].x); a1 += bfhi(us[u].x);
          a2 += bflo(us[u].y); a3 += bfhi(us[u].y);
          a4 += bflo(us[u].z); a5 += bfhi(us[u].z);
          a6 += bflo(us[u].w); a7 += bfhi(us[u].w);
        }
      }
    }
    // combine the two groups' disjoint neighbor sums (lane f8 <-> f8^8)
    a0 = dpp_addf<0x128>(a0); a1 = dpp_addf<0x128>(a1);
    a2 = dpp_addf<0x128>(a2); a3 = dpp_addf<0x128>(a3);
    a4 = dpp_addf<0x128>(a4); a5 = dpp_addf<0x128>(a5);
    a6 = dpp_addf<0x128>(a6); a7 = dpp_addf<0x128>(a7);
    if (i < n && g == 0) {
      float rdeg = 1.f / fmaxf((float)(s1 - s0), 1.f);
      uint4 w;
      w.x = pkbf(a0 * rdeg, a1 * rdeg);
      w.y = pkbf(a2 * rdeg, a3 * rdeg);
      w.z = pkbf(a4 * rdeg, a5 * rdeg);
      w.w = pkbf(a6 * rdeg, a7 * rdeg);
      ((uint4*)aggout)[(size_t)i * 8 + l8] = w;
    }
  }
}

// ---------------- node linear + LN + relu via MFMA, 2-set pipeline ----------

__global__ __launch_bounds__(256) void node_k(
    const ushort* __restrict__ agg, const ushort* __restrict__ selfb,
    const float* __restrict__ wl, const float* __restrict__ wr,
    const float* __restrict__ bias, const float* __restrict__ g, const float* __restrict__ lb,
    ushort* __restrict__ outb, int n) {
  __shared__ ushort wt[64 * 128];   // [n][k] swizzled, 16KB
  const int tid = threadIdx.x;
  for (int i = tid; i < 8192; i += 256) {
    int k = i >> 6, nn = i & 63;
    float v = (k < 64) ? wl[k * 64 + nn] : wr[(k - 64) * 64 + nn];
    wt[nn * 128 + (((k >> 3) ^ (nn & 7)) * 8) + (k & 7)] = bfbits(v);
  }
  __syncthreads();
  const int lane = tid & 63, wid = tid >> 6;
  const int ln = lane & 15, q = lane >> 4;
  float bias_n[4], g_n[4], lb_n[4];
  #pragma unroll
  for (int nt = 0; nt < 4; nt++) {
    bias_n[nt] = bias[nt * 16 + ln];
    g_n[nt] = g[nt * 16 + ln];
    lb_n[nt] = lb[nt * 16 + ln];
  }
  const int ntiles = (n + 15) >> 4;
  const int S = gridDim.x * 4;
  int t0 = blockIdx.x * 4 + wid;

  auto loadfrag = [&](FragU (&afr)[4], int t) {
    int tc = t < ntiles ? t : ntiles - 1;
    int node = tc * 16 + ln;
    int nc = node < n ? node : n - 1;
    #pragma unroll
    for (int kk = 0; kk < 2; kk++) {
      afr[kk].v     = ((const uint4*)agg)[(size_t)nc * 8 + kk * 4 + q];
      afr[2 + kk].v = ((const uint4*)selfb)[(size_t)nc * 8 + kk * 4 + q];
    }
  };

  auto compute = [&](FragU (&afr)[4], int t) {
    ffrag acc[4];
    #pragma unroll
    for (int nt = 0; nt < 4; nt++) acc[nt] = ffrag{0.f, 0.f, 0.f, 0.f};
    #pragma unroll
    for (int kk = 0; kk < 4; kk++) {
      bfrag a = afr[kk].f;
      #pragma unroll
      for (int nt = 0; nt < 4; nt++) {
        int nn = nt * 16 + ln;
        int b = kk * 4 + q;
        const bfrag* bp = (const bfrag*)&wt[nn * 128 + ((b ^ (nn & 7)) * 8)];
        acc[nt] = __builtin_amdgcn_mfma_f32_16x16x32_bf16(a, *bp, acc[nt], 0, 0, 0);
      }
    }
    #pragma unroll
    for (int r = 0; r < 4; r++) {
      int m = t * 16 + q * 4 + r;
      float o[4];
      #pragma unroll
      for (int nt = 0; nt < 4; nt++) o[nt] = acc[nt][r] + bias_n[nt];
      float s = (o[0] + o[1]) + (o[2] + o[3]);
      s = reduce16(s);
      float mu = s * (1.f / 64.f);
      float v2 = 0.f;
      #pragma unroll
      for (int nt = 0; nt < 4; nt++) { float d2 = o[nt] - mu; v2 += d2 * d2; }
      v2 = reduce16(v2);
      float rs = rsqrtf(v2 * (1.f / 64.f) + 1e-5f);
      if (m < n) {
        #pragma unroll
        for (int nt = 0; nt < 4; nt++) {
          float y = fmaxf((o[nt] - mu) * rs * g_n[nt] + lb_n[nt], 0.f);
          outb[(size_t)m * 64 + nt * 16 + ln] = bfbits(y);
        }
      }
    }
  };

  if (t0 >= ntiles) return;
  FragU fA[4], fB[4];
  loadfrag(fA, t0);
  loadfrag(fB, t0 + S);
  for (int t = t0; t < ntiles; t += 2 * S) {
    compute(fA, t);
    loadfrag(fA, t + 2 * S);        // issued 1 compute ahead of its wait
    if (t + S < ntiles) compute(fB, t + S);
    loadfrag(fB, t + 3 * S);
  }
}

// ---------------- edge classifier: 3-set pipeline, 2 blocks/CU (verified) ----
// Round-8 lesson: launch_bounds(256,4) caps unified VGPR+AGPR at 128 < the
// ~184 this kernel needs (112-reg W1 file + 3 z-sets) -> catastrophic spills
// (FETCH 201MB -> 1.27GB, 95 -> 396us). 2 blocks/CU is this kernel's ceiling;
// register residency beats occupancy here.

__global__ __launch_bounds__(256, 2) void edge_mfma_k(
    const int* __restrict__ ei, const float* __restrict__ ea,
    const ushort* __restrict__ zb,
    const float* __restrict__ cw1, const float* __restrict__ cb1,
    const float* __restrict__ cw2, const float* __restrict__ cb2,
    const float* __restrict__ cw3, const float* __restrict__ cb3,
    float* __restrict__ out, int E) {
  __shared__ ushort smem[64 * 256];   // 32KB: W1^T swizzled staging, then h1 tiles
  __shared__ ushort ws2[2048];        // 4KB: W2^T B-fragments [t2*2+kk][lane]*8
  const int tid = threadIdx.x;

  for (int i = tid; i < 224 * 64; i += 256) {
    int k = i >> 6, n = i & 63;
    int blk = k >> 3;
    smem[n * 256 + ((blk ^ (n & 7)) * 8) + (k & 7)] = bfbits(cw1[i]);
  }
  __syncthreads();

  const int lane = tid & 63, wid = tid >> 6;
  const int ln = lane & 15, q = lane >> 4;

  // W1 B-fragments -> 112 persistent regs (read LDS exactly once)
  FragU w1f[7][4];
  #pragma unroll
  for (int kk = 0; kk < 7; kk++) {
    #pragma unroll
    for (int tt = 0; tt < 4; tt++) {
      int n = tt * 16 + ln;
      int b = kk * 4 + q;
      w1f[kk][tt].v = *(const uint4*)&smem[n * 256 + ((b ^ (n & 7)) * 8)];
    }
  }
  // W2^T B-fragments -> LDS table
  if (wid == 0) {
    #pragma unroll
    for (int t2 = 0; t2 < 2; t2++) {
      #pragma unroll
      for (int kk = 0; kk < 2; kk++) {
        uint32_t w[4];
        #pragma unroll
        for (int p = 0; p < 4; p++) {
          int k = kk * 32 + q * 8 + p * 2;
          int n = t2 * 16 + ln;
          w[p] = pkbf(cw2[k * 32 + n], cw2[(k + 1) * 32 + n]);
        }
        *(uint4*)&ws2[((t2 * 2 + kk) * 64 + lane) * 8] = make_uint4(w[0], w[1], w[2], w[3]);
      }
    }
  }
  __syncthreads();                    // W1 staging dead; reuse as h1 tiles
  ushort* hb = &smem[wid * 1024];     // 16x64 bf16 per wave (2KB)

  float cb1v[4];
  #pragma unroll
  for (int t = 0; t < 4; t++) cb1v[t] = cb1[t * 16 + ln];
  float cb2a = cb2[ln], cb2b = cb2[16 + ln];
  float w3a = cw3[ln], w3b = cw3[16 + ln];
  float cb3v = cb3[0];

  const int nt = E >> 4;
  const int S = gridDim.x * 4;
  const int S3 = 3 * S;
  const int w0 = blockIdx.x * 4 + wid;
  const uint4* Z4 = (const uint4*)zb;
  const nf4* EA4 = (const nf4*)ea;

  FragU zA[4], zB[4], zC[4];
  int svA, dvA, svB, dvB, svC, dvC;

  // prologue: issue z for u, load ei values for u+S3 (in flight)
  auto prol = [&](FragU (&z)[4], int &sv, int &dv, int u) {
    int uc = u < nt ? u : nt - 1;
    int e = uc * 16 + ln;
    int s = __builtin_nontemporal_load(ei + e);
    int d = __builtin_nontemporal_load(ei + E + e);
    z[0].v = Z4[(size_t)s * 8 + q];
    z[1].v = Z4[(size_t)s * 8 + 4 + q];
    z[2].v = Z4[(size_t)d * 8 + q];
    z[3].v = Z4[(size_t)d * 8 + 4 + q];
    int un = u + S3 < nt ? u + S3 : nt - 1;
    sv = __builtin_nontemporal_load(ei + un * 16 + ln);
    dv = __builtin_nontemporal_load(ei + E + un * 16 + ln);
  };
  prol(zA, svA, dvA, w0);
  prol(zB, svB, dvB, w0 + S);
  prol(zC, svC, dvC, w0 + 2 * S);

  // one pipeline half: compute tile u from z; then refill z for u+S3 (in place)
  // and ei values for u+2*S3 (in place).
  auto half = [&](FragU (&z)[4], int &sv, int &dv, int u) {
    int uc = u < nt ? u : nt - 1;
    int e = uc * 16 + ln;
    // ea issue now; waited at kk=6 (last A-frag) ~400cy later
    nf4 l0 = __builtin_nontemporal_load(EA4 + (size_t)e * 8 + q * 2);
    nf4 l1 = __builtin_nontemporal_load(EA4 + (size_t)e * 8 + q * 2 + 1);

    ffrag acc1[4];
    #pragma unroll
    for (int tt = 0; tt < 4; tt++) acc1[tt] = ffrag{0.f, 0.f, 0.f, 0.f};
    #pragma unroll
    for (int kk = 0; kk < 7; kk++) {
      FragU af;
      if (kk < 4) af = z[kk];
      else if (kk < 6) {
        #pragma unroll
        for (int p = 0; p < 4; p++) af.u[p] = mul2bf(z[kk - 4].u[p], z[kk - 2].u[p]);
      } else {
        af.u[0] = pkbf(l0.x, l0.y); af.u[1] = pkbf(l0.z, l0.w);
        af.u[2] = pkbf(l1.x, l1.y); af.u[3] = pkbf(l1.z, l1.w);
      }
      bfrag a = af.f;
      #pragma unroll
      for (int tt = 0; tt < 4; tt++)
        acc1[tt] = __builtin_amdgcn_mfma_f32_16x16x32_bf16(a, w1f[kk][tt].f, acc1[tt], 0, 0, 0);
    }

    // refill this set: z gathers for u+S3 (addresses ready in sv/dv — no wait)
    {
      z[0].v = Z4[(size_t)sv * 8 + q];
      z[1].v = Z4[(size_t)sv * 8 + 4 + q];
      z[2].v = Z4[(size_t)dv * 8 + q];
      z[3].v = Z4[(size_t)dv * 8 + 4 + q];
      int uf = u + 2 * S3 < nt ? u + 2 * S3 : nt - 1;
      sv = __builtin_nontemporal_load(ei + uf * 16 + ln);
      dv = __builtin_nontemporal_load(ei + E + uf * 16 + ln);
    }

    // h1 = relu(acc1 + cb1) -> swizzled LDS transpose (C-layout -> A-layout)
    #pragma unroll
    for (int tt = 0; tt < 4; tt++) {
      #pragma unroll
      for (int r = 0; r < 4; r++) {
        int m = q * 4 + r;
        int col = tt * 16 + ln;
        float v = fmaxf(acc1[tt][r] + cb1v[tt], 0.f);
        hb[m * 64 + (((col >> 3) ^ (m & 7)) * 8) + (col & 7)] = bfbits(v);
      }
    }

    ffrag acc2[2];
    acc2[0] = ffrag{0.f, 0.f, 0.f, 0.f};
    acc2[1] = ffrag{0.f, 0.f, 0.f, 0.f};
    #pragma unroll
    for (int kk = 0; kk < 2; kk++) {
      int b = kk * 4 + q;
      const bfrag* ap = (const bfrag*)&hb[ln * 64 + ((b ^ (ln & 7)) * 8)];
      bfrag a2 = *ap;
      const bfrag* b0p = (const bfrag*)&ws2[((0 * 2 + kk) * 64 + lane) * 8];
      const bfrag* b1p = (const bfrag*)&ws2[((1 * 2 + kk) * 64 + lane) * 8];
      acc2[0] = __builtin_amdgcn_mfma_f32_16x16x32_bf16(a2, *b0p, acc2[0], 0, 0, 0);
      acc2[1] = __builtin_amdgcn_mfma_f32_16x16x32_bf16(a2, *b1p, acc2[1], 0, 0, 0);
    }

    float p0 = fmaxf(acc2[0][0] + cb2a, 0.f) * w3a + fmaxf(acc2[1][0] + cb2b, 0.f) * w3b;
    float p1 = fmaxf(acc2[0][1] + cb2a, 0.f) * w3a + fmaxf(acc2[1][1] + cb2b, 0.f) * w3b;
    float p2 = fmaxf(acc2[0][2] + cb2a, 0.f) * w3a + fmaxf(acc2[1][2] + cb2b, 0.f) * w3b;
    float p3 = fmaxf(acc2[0][3] + cb2a, 0.f) * w3a + fmaxf(acc2[1][3] + cb2b, 0.f) * w3b;
    p0 = reduce16(p0); p1 = reduce16(p1); p2 = reduce16(p2); p3 = reduce16(p3);
    float keep = (ln == 0) ? p0 : (ln == 1) ? p1 : (ln == 2) ? p2 : p3;
    if (u < nt && ln < 4)
      __builtin_nontemporal_store(keep + cb3v, &out[u * 16 + q * 4 + ln]);
  };

  for (int t = w0; t < nt; t += S3) {
    half(zA, svA, dvA, t);
    half(zB, svB, dvB, t + S);
    half(zC, svC, dvC, t + 2 * S);
  }
}

// ---------------- launch ----------------

extern "C" void kernel_launch(void* const* d_in, const int* in_sizes, int n_in,
                              void* d_out, int out_size, void* d_ws, size_t ws_size,
                              hipStream_t stream) {
  const float* x   = (const float*)d_in[0];
  const int*   ei  = (const int*)d_in[1];
  const float* ea  = (const float*)d_in[2];
  const float* wl0 = (const float*)d_in[3];
  const float* wr0 = (const float*)d_in[4];
  const float* b0  = (const float*)d_in[5];
  const float* g0  = (const float*)d_in[6];
  const float* lb0 = (const float*)d_in[7];
  const float* wl1 = (const float*)d_in[8];
  const float* wr1 = (const float*)d_in[9];
  const float* b1  = (const float*)d_in[10];
  const float* g1  = (const float*)d_in[11];
  const float* lb1 = (const float*)d_in[12];
  const float* cw1 = (const float*)d_in[13];
  const float* cb1 = (const float*)d_in[14];
  const float* cw2 = (const float*)d_in[15];
  const float* cb2 = (const float*)d_in[16];
  const float* cw3 = (const float*)d_in[17];
  const float* cb3 = (const float*)d_in[18];
  float* out = (float*)d_out;
  const int N = N_NODES, E = N_EDGES;
  const int NB = (N + 1023) / 1024;

  uintptr_t pp = (uintptr_t)d_ws;
  auto alloc = [&](size_t bytes) {
    uintptr_t r = (pp + 255) & ~(uintptr_t)255; pp = r + bytes; return (void*)r;
  };
  int* deg  = (int*)alloc((size_t)N * 4);
  int* off  = (int*)alloc((size_t)(N + 1) * 4);
  int* rank = (int*)alloc((size_t)E * 4);
  int* csr  = (int*)alloc((size_t)E * 4);
  int* bsum = (int*)alloc((size_t)NB * 4);
  int* bpre = (int*)alloc((size_t)NB * 4);
  ushort* xb  = (ushort*)alloc((size_t)N * 64 * 2);
  ushort* agg = (ushort*)alloc((size_t)N * 64 * 2);
  ushort* hb  = (ushort*)alloc((size_t)N * 64 * 2);
  ushort* zb  = (ushort*)alloc((size_t)N * 64 * 2);

  hipMemsetAsync(deg, 0, (size_t)N * 4, stream);
  cvt_k<<<(N * 32 + 255) / 256, 256, 0, stream>>>(x, xb, N * 32);
  hist_k<<<(E + 255) / 256, 256, 0, stream>>>(ei, deg, rank, E);
  scan1_k<<<NB, 1024, 0, stream>>>(deg, off, bsum, N);
  scan2_k<<<1, 64, 0, stream>>>(bsum, bpre, off, NB, N);
  scan3_k<<<NB, 1024, 0, stream>>>(off, bpre, N);
  fill_k<<<(E + 255) / 256, 256, 0, stream>>>(ei, off, rank, csr, E);
  // layer 0
  agg_k<<<2048, 256, 0, stream>>>(xb, off, csr, agg, N);
  node_k<<<1024, 256, 0, stream>>>(agg, xb, wl0, wr0, b0, g0, lb0, hb, N);
  // layer 1
  agg_k<<<2048, 256, 0, stream>>>(hb, off, csr, agg, N);
  node_k<<<1024, 256, 0, stream>>>(agg, hb, wl1, wr1, b1, g1, lb1, zb, N);
  // edge classifier
  edge_mfma_k<<<512, 256, 0, stream>>>(ei, ea, zb, cw1, cb1, cw2, cb2, cw3, cb3, out, E);
}